// Round 1
// baseline (1615.280 us; speedup 1.0000x reference)
//
#include <hip/hip_runtime.h>

// Tsit5 tableau (fp32-rounded, matches reference's weak-typed fp32 math)
__device__ __constant__ float dA[6][5] = {
  {0.f, 0.f, 0.f, 0.f, 0.f},
  {0.161f, 0.f, 0.f, 0.f, 0.f},
  {-0.008480655492356989f, 0.335480655492357f, 0.f, 0.f, 0.f},
  {2.8971530571054935f, -6.359448489975075f, 4.3622954328695815f, 0.f, 0.f},
  {5.325864828439257f, -11.748883564062828f, 7.4955393428898365f, -0.09249506636175525f, 0.f},
  {5.86145544294642f, -12.92096931784711f, 8.159367898576159f, -0.071584973281401f, -0.028269050394068383f}
};
__device__ __constant__ float dC[6] = {0.f, 0.161f, 0.327f, 0.9f, 0.9800255409045097f, 1.0f};
__device__ __constant__ float dB[6] = {0.09646076681806523f, 0.01f, 0.4798896504144996f,
                                       1.379008574103742f, -3.290069515436081f, 2.324710524099774f};

#define BUFS 132            // padded row stride for activation buffers (breaks bank aliasing)
#define NSTEPS 49

// LDS layout (float offsets)
#define OFF_W0T 0           // [68][128]  (rows 65..67 zero-padded)
#define OFF_W1T 8704        // [128][128]
#define OFF_W2T 25088       // [128][64]
#define OFF_B0  33280       // [128]
#define OFF_B1  33408       // [128]
#define OFF_B2  33536       // [64]
#define OFF_BI  33600       // [8][132]  stage input / h2 ping
#define OFF_BH  34656       // [8][132]  h1 pong
#define OFF_K   35712       // [6][8][64] stage derivatives k1..k6
#define OFF_Y   38784       // [8][64]   current state
#define LDS_FLOATS 39296    // 157184 bytes

extern "C" __global__ void __launch_bounds__(256, 1)
node_solve(const float* __restrict__ y0, const float* __restrict__ ts,
           const float* __restrict__ gw0, const float* __restrict__ gb0,
           const float* __restrict__ gw1, const float* __restrict__ gb1,
           const float* __restrict__ gw2, const float* __restrict__ gb2,
           float* __restrict__ out)
{
    extern __shared__ float lds[];
    float* sW0T = lds + OFF_W0T;
    float* sW1T = lds + OFF_W1T;
    float* sW2T = lds + OFF_W2T;
    float* sB0  = lds + OFF_B0;
    float* sB1  = lds + OFF_B1;
    float* sB2  = lds + OFF_B2;
    float* bufI = lds + OFF_BI;
    float* bufH = lds + OFF_BH;
    float* sK   = lds + OFF_K;
    float* sY   = lds + OFF_Y;

    const int tid = threadIdx.x;
    const int r   = tid & 7;        // row within block (0..7)
    const int jq  = tid >> 3;       // 0..31
    const int jc  = jq * 4;         // output-neuron group for layers 1/2
    const int d0  = jq * 2;         // state-dim pair for L3 / build / update
    const int row0 = blockIdx.x * 8;

    // ---- one-time staging: transpose weights into LDS ----
    for (int idx = tid; idx < 128 * 65; idx += 256) {
        int j = idx / 65, i = idx - j * 65;
        sW0T[i * 128 + j] = gw0[idx];
    }
    for (int idx = tid; idx < 3 * 128; idx += 256) sW0T[65 * 128 + idx] = 0.f; // pad rows
    for (int idx = tid; idx < 128 * 128; idx += 256) {
        int j = idx >> 7, i = idx & 127;
        sW1T[i * 128 + j] = gw1[idx];
    }
    for (int idx = tid; idx < 64 * 128; idx += 256) {
        int d = idx >> 7, i = idx & 127;
        sW2T[i * 64 + d] = gw2[idx];
    }
    if (tid < 128) { sB0[tid] = gb0[tid]; sB1[tid] = gb1[tid]; }
    if (tid < 64)  { sB2[tid] = gb2[tid]; }
    // zero k storage (stage-0 reads it with zero coeffs; must be finite) and buffers (NaN safety)
    for (int idx = tid; idx < 6 * 8 * 64; idx += 256) sK[idx] = 0.f;
    for (int idx = tid; idx < 2 * 8 * BUFS; idx += 256) bufI[idx] = 0.f;
    // load state rows
    for (int idx = tid; idx < 8 * 64; idx += 256) {
        int rr = idx >> 6, d = idx & 63;
        sY[rr * 64 + d] = y0[(row0 + rr) * 64 + d];
    }

    const float t0v = ts[0];
    const float dtv = ts[1] - ts[0];

    __syncthreads();

    for (int step = 0; step < NSTEPS; ++step) {
        const float tcur = t0v + (float)step * dtv;

        for (int s = 0; s < 6; ++s) {
            // ---- build stage input: in[r][0]=t_s, in[r][1+d] = y_d + dt*sum_q A[s][q]*k_q[d]
            {
                float s0 = 0.f, s1 = 0.f;
                #pragma unroll
                for (int q = 0; q < 5; ++q) {
                    float a = dA[s][q];
                    s0 += a * sK[q * 512 + r * 64 + d0];
                    s1 += a * sK[q * 512 + r * 64 + d0 + 1];
                }
                bufI[r * BUFS + 1 + d0]     = sY[r * 64 + d0]     + dtv * s0;
                bufI[r * BUFS + 1 + d0 + 1] = sY[r * 64 + d0 + 1] + dtv * s1;
                if (jq == 0) bufI[r * BUFS] = tcur + dC[s] * dtv;
            }
            __syncthreads();

            // ---- layer 1: [68] x W0T -> h1[r][jc..jc+3], relu ----
            {
                float a0 = 0.f, a1 = 0.f, a2 = 0.f, a3 = 0.f;
                const float* xin = bufI + r * BUFS;
                const float* wp  = sW0T + jc;
                #pragma unroll
                for (int i4 = 0; i4 < 17; ++i4) {
                    float4 x   = *(const float4*)(xin + i4 * 4);
                    float4 w0v = *(const float4*)(wp + (i4 * 4 + 0) * 128);
                    float4 w1v = *(const float4*)(wp + (i4 * 4 + 1) * 128);
                    float4 w2v = *(const float4*)(wp + (i4 * 4 + 2) * 128);
                    float4 w3v = *(const float4*)(wp + (i4 * 4 + 3) * 128);
                    a0 += x.x * w0v.x; a1 += x.x * w0v.y; a2 += x.x * w0v.z; a3 += x.x * w0v.w;
                    a0 += x.y * w1v.x; a1 += x.y * w1v.y; a2 += x.y * w1v.z; a3 += x.y * w1v.w;
                    a0 += x.z * w2v.x; a1 += x.z * w2v.y; a2 += x.z * w2v.z; a3 += x.z * w2v.w;
                    a0 += x.w * w3v.x; a1 += x.w * w3v.y; a2 += x.w * w3v.z; a3 += x.w * w3v.w;
                }
                float4 bb = *(const float4*)(sB0 + jc);
                float4 h;
                h.x = fmaxf(a0 + bb.x, 0.f);
                h.y = fmaxf(a1 + bb.y, 0.f);
                h.z = fmaxf(a2 + bb.z, 0.f);
                h.w = fmaxf(a3 + bb.w, 0.f);
                *(float4*)(bufH + r * BUFS + jc) = h;
            }
            __syncthreads();

            // ---- layer 2: [128] x W1T -> h2 into bufI[r][jc..jc+3], relu ----
            {
                float a0 = 0.f, a1 = 0.f, a2 = 0.f, a3 = 0.f;
                const float* xin = bufH + r * BUFS;
                const float* wp  = sW1T + jc;
                #pragma unroll
                for (int i4 = 0; i4 < 32; ++i4) {
                    float4 x   = *(const float4*)(xin + i4 * 4);
                    float4 w0v = *(const float4*)(wp + (i4 * 4 + 0) * 128);
                    float4 w1v = *(const float4*)(wp + (i4 * 4 + 1) * 128);
                    float4 w2v = *(const float4*)(wp + (i4 * 4 + 2) * 128);
                    float4 w3v = *(const float4*)(wp + (i4 * 4 + 3) * 128);
                    a0 += x.x * w0v.x; a1 += x.x * w0v.y; a2 += x.x * w0v.z; a3 += x.x * w0v.w;
                    a0 += x.y * w1v.x; a1 += x.y * w1v.y; a2 += x.y * w1v.z; a3 += x.y * w1v.w;
                    a0 += x.z * w2v.x; a1 += x.z * w2v.y; a2 += x.z * w2v.z; a3 += x.z * w2v.w;
                    a0 += x.w * w3v.x; a1 += x.w * w3v.y; a2 += x.w * w3v.z; a3 += x.w * w3v.w;
                }
                float4 bb = *(const float4*)(sB1 + jc);
                float4 h;
                h.x = fmaxf(a0 + bb.x, 0.f);
                h.y = fmaxf(a1 + bb.y, 0.f);
                h.z = fmaxf(a2 + bb.z, 0.f);
                h.w = fmaxf(a3 + bb.w, 0.f);
                *(float4*)(bufI + r * BUFS + jc) = h;
            }
            __syncthreads();

            // ---- layer 3: [128] x W2T -> k_s[r][d0..d0+1] (registers-free, straight to LDS) ----
            {
                float a0 = 0.f, a1 = 0.f;
                const float* xin = bufI + r * BUFS;
                const float* wp  = sW2T + d0;
                #pragma unroll
                for (int i4 = 0; i4 < 32; ++i4) {
                    float4 x   = *(const float4*)(xin + i4 * 4);
                    float2 w0v = *(const float2*)(wp + (i4 * 4 + 0) * 64);
                    float2 w1v = *(const float2*)(wp + (i4 * 4 + 1) * 64);
                    float2 w2v = *(const float2*)(wp + (i4 * 4 + 2) * 64);
                    float2 w3v = *(const float2*)(wp + (i4 * 4 + 3) * 64);
                    a0 += x.x * w0v.x + x.y * w1v.x + x.z * w2v.x + x.w * w3v.x;
                    a1 += x.x * w0v.y + x.y * w1v.y + x.z * w2v.y + x.w * w3v.y;
                }
                float* kb = sK + s * 512 + r * 64;
                kb[d0]     = a0 + sB2[d0];
                kb[d0 + 1] = a1 + sB2[d0 + 1];
            }
            __syncthreads();
        }

        // ---- y update: y += dt * sum_s B[s] * k_s  (owner-thread, no barrier needed) ----
        {
            float s0 = 0.f, s1 = 0.f;
            #pragma unroll
            for (int q = 0; q < 6; ++q) {
                float b = dB[q];
                s0 += b * sK[q * 512 + r * 64 + d0];
                s1 += b * sK[q * 512 + r * 64 + d0 + 1];
            }
            sY[r * 64 + d0]     += dtv * s0;
            sY[r * 64 + d0 + 1] += dtv * s1;
        }
    }

    // ---- write out (owner mapping: same thread wrote these sY entries) ----
    {
        const int g = (row0 + r) * 64 + d0;
        out[g]     = sY[r * 64 + d0];
        out[g + 1] = sY[r * 64 + d0 + 1];
    }
}

extern "C" void kernel_launch(void* const* d_in, const int* in_sizes, int n_in,
                              void* d_out, int out_size, void* d_ws, size_t ws_size,
                              hipStream_t stream) {
    const float* y0 = (const float*)d_in[0];
    const float* ts = (const float*)d_in[1];
    const float* w0 = (const float*)d_in[2];
    const float* b0 = (const float*)d_in[3];
    const float* w1 = (const float*)d_in[4];
    const float* b1 = (const float*)d_in[5];
    const float* w2 = (const float*)d_in[6];
    const float* b2 = (const float*)d_in[7];
    float* out = (float*)d_out;

    const size_t lds_bytes = LDS_FLOATS * sizeof(float);  // 157184 B < 160 KiB
    // Opt-in to >64KB dynamic LDS (idempotent; not a stream op — capture-safe).
    (void)hipFuncSetAttribute((const void*)node_solve,
                              hipFuncAttributeMaxDynamicSharedMemorySize, (int)lds_bytes);

    node_solve<<<dim3(256), dim3(256), lds_bytes, stream>>>(y0, ts, w0, b0, w1, b1, w2, b2, out);
}